// Round 1
// baseline (84.154 us; speedup 1.0000x reference)
//
#include <hip/hip_runtime.h>

#define TT 1024
#define FF 512
#define BB 32

// ---------------- Kernel A: ws[b,t] = sigmoid(x[b,t,:] . w + bias) ----------
// One wave (64 lanes) per row; lane i handles 8 contiguous floats (2x float4).
// Accumulate in double so our dot is closer to the exact value than any f32
// summation order -> minimizes valley-comparison tie flips vs the reference.
__global__ __launch_bounds__(256) void gate_kernel(const float* __restrict__ x,
                                                   const float* __restrict__ w,
                                                   const float* __restrict__ bias,
                                                   float* __restrict__ ws) {
    int wid  = threadIdx.x >> 6;
    int lane = threadIdx.x & 63;
    int row  = blockIdx.x * 4 + wid;              // 0 .. 32767
    const float4* xr = (const float4*)(x + (size_t)row * FF);
    const float4* wr = (const float4*)w;
    float4 x0 = xr[lane * 2],     x1 = xr[lane * 2 + 1];
    float4 w0 = wr[lane * 2],     w1 = wr[lane * 2 + 1];
    double acc = (double)x0.x * w0.x + (double)x0.y * w0.y +
                 (double)x0.z * w0.z + (double)x0.w * w0.w +
                 (double)x1.x * w1.x + (double)x1.y * w1.y +
                 (double)x1.z * w1.z + (double)x1.w * w1.w;
    #pragma unroll
    for (int off = 32; off; off >>= 1) acc += __shfl_down(acc, off);
    if (lane == 0) {
        float z = (float)acc + bias[0];
        ws[row] = 1.0f / (1.0f + expf(-z));
    }
}

// ---------------- Kernel B: per-batch valley detect + segment build ---------
// One block of 1024 threads per batch. valley[t] = strict local min (t in
// [1,T-2]; endpoints are never valleys since ws>0). Segments:
//   starts = [0, v1, ..., vk], ends = [min(v1+2,T), ..., min(vk+2,T), T]
// den[s] = max(sum ws over [start,end), EPS) via an in-LDS prefix sum.
__global__ __launch_bounds__(1024) void seg_kernel(const float* __restrict__ ws,
                                                   int* __restrict__ seg_start,
                                                   int* __restrict__ seg_end,
                                                   float* __restrict__ den,
                                                   int* __restrict__ counts) {
    int b = blockIdx.x, t = threadIdx.x;
    __shared__ float w[TT];
    __shared__ float p[TT];
    __shared__ unsigned long long words[16];
    __shared__ float wavesum[16];

    w[t] = ws[b * TT + t];
    __syncthreads();

    float wt = w[t];
    bool valley = (t > 0) && (t < TT - 1) && (wt < w[t - 1]) && (wt < w[t + 1]);
    unsigned long long m = __ballot(valley);
    int wid = t >> 6, lane = t & 63;
    if (lane == 0) words[wid] = m;

    // inclusive wave scan of ws
    float s = wt;
    #pragma unroll
    for (int off = 1; off < 64; off <<= 1) {
        float v = __shfl_up(s, off);
        if (lane >= off) s += v;
    }
    if (lane == 63) wavesum[wid] = s;
    __syncthreads();
    float offset = 0.0f;
    for (int i = 0; i < wid; ++i) offset += wavesum[i];
    p[t] = s + offset;                     // inclusive prefix over the row
    __syncthreads();

    if (t == 0) {
        int cnt = 0, prev = 0;
        for (int wi = 0; wi < 16; ++wi) {
            unsigned long long mm = words[wi];
            while (mm) {
                int bit = __builtin_ctzll(mm);
                mm &= mm - 1;
                int v = wi * 64 + bit;     // valley position, in ascending order
                int en = v + 2; if (en > TT) en = TT;
                seg_start[b * TT + cnt] = prev;
                seg_end  [b * TT + cnt] = en;
                float d = p[en - 1] - (prev > 0 ? p[prev - 1] : 0.0f);
                den[b * TT + cnt] = fmaxf(d, 1e-6f);
                prev = v;
                ++cnt;
            }
        }
        seg_start[b * TT + cnt] = prev;
        seg_end  [b * TT + cnt] = TT;
        den[b * TT + cnt] = fmaxf(p[TT - 1] - (prev > 0 ? p[prev - 1] : 0.0f), 1e-6f);
        ++cnt;
        counts[b] = cnt;
    }
}

// ---------------- Kernel C: out[b,s,:] = sum_t ws*x / den  ------------------
// One block of 128 threads per (b,s); each thread owns 4 contiguous features.
__global__ __launch_bounds__(128) void out_kernel(const float* __restrict__ x,
                                                  const float* __restrict__ ws,
                                                  const int* __restrict__ seg_start,
                                                  const int* __restrict__ seg_end,
                                                  const float* __restrict__ den,
                                                  const int* __restrict__ counts,
                                                  float* __restrict__ out) {
    int bs = blockIdx.x;                  // b*1024 + s
    int b  = bs >> 10;
    int s  = bs & 1023;
    int f  = threadIdx.x * 4;
    float4* o = (float4*)(out + (size_t)bs * FF + f);
    if (s >= counts[b]) {                 // zero-filled unused segment rows
        *o = make_float4(0.f, 0.f, 0.f, 0.f);
        return;
    }
    int st = seg_start[bs], en = seg_end[bs];
    float d = den[bs];
    const float* xb = x + (size_t)b * TT * FF;
    float4 acc = make_float4(0.f, 0.f, 0.f, 0.f);
    for (int t = st; t < en; ++t) {
        float wt = ws[b * TT + t];
        float4 xv = *(const float4*)(xb + (size_t)t * FF + f);
        acc.x += wt * xv.x; acc.y += wt * xv.y;
        acc.z += wt * xv.z; acc.w += wt * xv.w;
    }
    *o = make_float4(acc.x / d, acc.y / d, acc.z / d, acc.w / d);
}

// ---------------- Kernel D: new_mask ----------------------------------------
__global__ __launch_bounds__(1024) void mask_kernel(const int* __restrict__ counts,
                                                    const int* __restrict__ seq_len,
                                                    float* __restrict__ mask) {
    int b = blockIdx.x, s = threadIdx.x;
    int maxc = 0;
    #pragma unroll
    for (int i = 0; i < BB; ++i) maxc = max(maxc, counts[i]);
    float l0 = (float)seq_len[0];
    float v  = ((float)seq_len[b] / l0) * (float)maxc;   // match jnp f32 order
    int nl = (int)v;                                     // trunc like astype(int32)
    mask[b * TT + s] = (s < nl) ? 1.0f : 0.0f;
}

extern "C" void kernel_launch(void* const* d_in, const int* in_sizes, int n_in,
                              void* d_out, int out_size, void* d_ws, size_t ws_size,
                              hipStream_t stream) {
    const float* x    = (const float*)d_in[0];
    const float* aw   = (const float*)d_in[1];
    const float* ab   = (const float*)d_in[2];
    const int*   seq  = (const int*)d_in[3];
    float* out = (float*)d_out;

    // workspace layout (floats): ws[32768] | den[32768] | sstart[32768] |
    //                            send[32768] | counts[32]
    float* ws     = (float*)d_ws;
    float* den    = ws + BB * TT;
    int*   sstart = (int*)(ws + 2 * BB * TT);
    int*   send   = (int*)(ws + 3 * BB * TT);
    int*   counts = (int*)(ws + 4 * BB * TT);

    gate_kernel<<<BB * TT / 4, 256, 0, stream>>>(x, aw, ab, ws);
    seg_kernel<<<BB, 1024, 0, stream>>>(ws, sstart, send, den, counts);
    out_kernel<<<BB * TT, 128, 0, stream>>>(x, ws, sstart, send, den, counts, out);
    mask_kernel<<<BB, 1024, 0, stream>>>(counts, seq, out + (size_t)BB * TT * FF);
}

// Round 2
// 46.427 us; speedup vs baseline: 1.8126x; 1.8126x over previous
//
#include <hip/hip_runtime.h>

#define TT 1024
#define FF 512
#define BB 32
#define MAXSEG 513   // valleys are never adjacent -> cnt <= T/2 + 1

// ---------------- Kernel A: ws[b,t] = sigmoid(x[b,t,:] . w + bias) ----------
// One wave (64 lanes) per row; lane i handles 8 contiguous floats (2x float4).
// Double accumulation: closest to exact dot -> minimizes strict-< valley tie
// flips vs the numpy reference.
__global__ __launch_bounds__(256) void gate_kernel(const float* __restrict__ x,
                                                   const float* __restrict__ w,
                                                   const float* __restrict__ bias,
                                                   float* __restrict__ ws) {
    int wid  = threadIdx.x >> 6;
    int lane = threadIdx.x & 63;
    int row  = blockIdx.x * 4 + wid;              // 0 .. 32767
    const float4* xr = (const float4*)(x + (size_t)row * FF);
    const float4* wr = (const float4*)w;
    float4 x0 = xr[lane * 2],     x1 = xr[lane * 2 + 1];
    float4 w0 = wr[lane * 2],     w1 = wr[lane * 2 + 1];
    double acc = (double)x0.x * w0.x + (double)x0.y * w0.y +
                 (double)x0.z * w0.z + (double)x0.w * w0.w +
                 (double)x1.x * w1.x + (double)x1.y * w1.y +
                 (double)x1.z * w1.z + (double)x1.w * w1.w;
    #pragma unroll
    for (int off = 32; off; off >>= 1) acc += __shfl_down(acc, off);
    if (lane == 0) {
        float z = (float)acc + bias[0];
        ws[row] = 1.0f / (1.0f + expf(-z));
    }
}

// ---------------- Kernel B: per-batch valley detect + segment build ---------
// Fully parallel: valley rank via prefix-popcount of ballot words; the valley
// with rank r at position v is the START of segment r+1 and the END of
// segment r (min(v+2,T)). Thread 0 caps start[0]=0, end[k]=T. den from an
// in-LDS inclusive prefix sum of ws.
__global__ __launch_bounds__(1024) void seg_kernel(const float* __restrict__ ws,
                                                   int* __restrict__ seg_start,
                                                   int* __restrict__ seg_end,
                                                   float* __restrict__ den,
                                                   int* __restrict__ counts) {
    int b = blockIdx.x, t = threadIdx.x;
    __shared__ float w[TT];
    __shared__ float p[TT];
    __shared__ unsigned long long words[16];
    __shared__ float wavesum[16];
    __shared__ int sst[MAXSEG];
    __shared__ int sen[MAXSEG];

    w[t] = ws[b * TT + t];
    __syncthreads();

    float wt = w[t];
    bool valley = (t > 0) && (t < TT - 1) && (wt < w[t - 1]) && (wt < w[t + 1]);
    unsigned long long m = __ballot(valley);
    int wid = t >> 6, lane = t & 63;
    if (lane == 0) words[wid] = m;

    // inclusive wave scan of ws (for den)
    float s = wt;
    #pragma unroll
    for (int off = 1; off < 64; off <<= 1) {
        float v = __shfl_up(s, off);
        if (lane >= off) s += v;
    }
    if (lane == 63) wavesum[wid] = s;
    __syncthreads();

    float offset = 0.0f;
    for (int i = 0; i < wid; ++i) offset += wavesum[i];
    p[t] = s + offset;                     // inclusive prefix over the row

    // exclusive prefix popcount -> valley rank; also total valley count
    int before = __popcll(m & ((1ull << lane) - 1ull));
    int total = 0;
    for (int i = 0; i < 16; ++i) {
        int pc = __popcll(words[i]);
        if (i < wid) before += pc;
        total += pc;
    }
    if (valley) {
        int en = t + 2; if (en > TT) en = TT;
        sst[before + 1] = t;               // start of segment rank+1
        sen[before]     = en;              // end of segment rank
    }
    if (t == 0) {
        sst[0]     = 0;
        sen[total] = TT;
        counts[b]  = total + 1;
    }
    __syncthreads();

    int cnt = total + 1;
    if (t < cnt) {
        int st = sst[t], en = sen[t];
        seg_start[b * TT + t] = st;
        seg_end  [b * TT + t] = en;
        float d = p[en - 1] - (st > 0 ? p[st - 1] : 0.0f);
        den[b * TT + t] = fmaxf(d, 1e-6f);
    }
}

// ---------------- Kernel C: out[b,s,:] = sum_t ws*x / den  ------------------
// One block of 128 threads per (b,s); each thread owns 4 contiguous features.
__global__ __launch_bounds__(128) void out_kernel(const float* __restrict__ x,
                                                  const float* __restrict__ ws,
                                                  const int* __restrict__ seg_start,
                                                  const int* __restrict__ seg_end,
                                                  const float* __restrict__ den,
                                                  const int* __restrict__ counts,
                                                  float* __restrict__ out) {
    int bs = blockIdx.x;                  // b*1024 + s
    int b  = bs >> 10;
    int s  = bs & 1023;
    int f  = threadIdx.x * 4;
    float4* o = (float4*)(out + (size_t)bs * FF + f);
    if (s >= counts[b]) {                 // zero-filled unused segment rows
        *o = make_float4(0.f, 0.f, 0.f, 0.f);
        return;
    }
    int st = seg_start[bs], en = seg_end[bs];
    float d = den[bs];
    const float* xb = x + (size_t)b * TT * FF;
    float4 acc = make_float4(0.f, 0.f, 0.f, 0.f);
    for (int t = st; t < en; ++t) {
        float wt = ws[b * TT + t];
        float4 xv = *(const float4*)(xb + (size_t)t * FF + f);
        acc.x += wt * xv.x; acc.y += wt * xv.y;
        acc.z += wt * xv.z; acc.w += wt * xv.w;
    }
    *o = make_float4(acc.x / d, acc.y / d, acc.z / d, acc.w / d);
}

// ---------------- Kernel D: new_mask ----------------------------------------
__global__ __launch_bounds__(1024) void mask_kernel(const int* __restrict__ counts,
                                                    const int* __restrict__ seq_len,
                                                    float* __restrict__ mask) {
    int b = blockIdx.x, s = threadIdx.x;
    int maxc = 0;
    #pragma unroll
    for (int i = 0; i < BB; ++i) maxc = max(maxc, counts[i]);
    float l0 = (float)seq_len[0];
    float v  = ((float)seq_len[b] / l0) * (float)maxc;   // match jnp f32 order
    int nl = (int)v;                                     // trunc like astype(int32)
    mask[b * TT + s] = (s < nl) ? 1.0f : 0.0f;
}

extern "C" void kernel_launch(void* const* d_in, const int* in_sizes, int n_in,
                              void* d_out, int out_size, void* d_ws, size_t ws_size,
                              hipStream_t stream) {
    const float* x    = (const float*)d_in[0];
    const float* aw   = (const float*)d_in[1];
    const float* ab   = (const float*)d_in[2];
    const int*   seq  = (const int*)d_in[3];
    float* out = (float*)d_out;

    // workspace layout (floats): ws[32768] | den[32768] | sstart[32768] |
    //                            send[32768] | counts[32]
    float* ws     = (float*)d_ws;
    float* den    = ws + BB * TT;
    int*   sstart = (int*)(ws + 2 * BB * TT);
    int*   send   = (int*)(ws + 3 * BB * TT);
    int*   counts = (int*)(ws + 4 * BB * TT);

    gate_kernel<<<BB * TT / 4, 256, 0, stream>>>(x, aw, ab, ws);
    seg_kernel<<<BB, 1024, 0, stream>>>(ws, sstart, send, den, counts);
    out_kernel<<<BB * TT, 128, 0, stream>>>(x, ws, sstart, send, den, counts, out);
    mask_kernel<<<BB, 1024, 0, stream>>>(counts, seq, out + (size_t)BB * TT * FF);
}

// Round 3
// 44.441 us; speedup vs baseline: 1.8936x; 1.0447x over previous
//
#include <hip/hip_runtime.h>

#define TT 1024
#define FF 512
#define BB 32
#define MAXSEG 513   // valleys are never adjacent -> cnt <= T/2 + 1

typedef float f32x4 __attribute__((ext_vector_type(4)));

__device__ __forceinline__ void nt_store4(float* p, f32x4 v) {
    __builtin_nontemporal_store(v, (f32x4*)p);
}

// ---------------- Kernel A: ws[b,t] = sigmoid(x[b,t,:] . w + bias) ----------
// One wave (64 lanes) per row; lane i handles 8 contiguous floats (2x float4).
// Double accumulation: closest to exact dot -> minimizes strict-< valley tie
// flips vs the numpy reference.
__global__ __launch_bounds__(256) void gate_kernel(const float* __restrict__ x,
                                                   const float* __restrict__ w,
                                                   const float* __restrict__ bias,
                                                   float* __restrict__ ws) {
    int wid  = threadIdx.x >> 6;
    int lane = threadIdx.x & 63;
    int row  = blockIdx.x * 4 + wid;              // 0 .. 32767
    const float4* xr = (const float4*)(x + (size_t)row * FF);
    const float4* wr = (const float4*)w;
    float4 x0 = xr[lane * 2],     x1 = xr[lane * 2 + 1];
    float4 w0 = wr[lane * 2],     w1 = wr[lane * 2 + 1];
    double acc = (double)x0.x * w0.x + (double)x0.y * w0.y +
                 (double)x0.z * w0.z + (double)x0.w * w0.w +
                 (double)x1.x * w1.x + (double)x1.y * w1.y +
                 (double)x1.z * w1.z + (double)x1.w * w1.w;
    #pragma unroll
    for (int off = 32; off; off >>= 1) acc += __shfl_down(acc, off);
    if (lane == 0) {
        float z = (float)acc + bias[0];
        ws[row] = 1.0f / (1.0f + expf(-z));
    }
}

// ---------------- Kernel B: per-batch valley detect + segment build ---------
// Fully parallel: valley rank via prefix-popcount of ballot words; valley with
// rank r at position v is the START of segment r+1 and the END of segment r
// (min(v+2,T)). den from an in-LDS inclusive prefix sum of ws.
__global__ __launch_bounds__(1024) void seg_kernel(const float* __restrict__ ws,
                                                   int* __restrict__ seg_start,
                                                   int* __restrict__ seg_end,
                                                   float* __restrict__ den,
                                                   int* __restrict__ counts) {
    int b = blockIdx.x, t = threadIdx.x;
    __shared__ float w[TT];
    __shared__ float p[TT];
    __shared__ unsigned long long words[16];
    __shared__ float wavesum[16];
    __shared__ int sst[MAXSEG];
    __shared__ int sen[MAXSEG];

    w[t] = ws[b * TT + t];
    __syncthreads();

    float wt = w[t];
    bool valley = (t > 0) && (t < TT - 1) && (wt < w[t - 1]) && (wt < w[t + 1]);
    unsigned long long m = __ballot(valley);
    int wid = t >> 6, lane = t & 63;
    if (lane == 0) words[wid] = m;

    // inclusive wave scan of ws (for den)
    float s = wt;
    #pragma unroll
    for (int off = 1; off < 64; off <<= 1) {
        float v = __shfl_up(s, off);
        if (lane >= off) s += v;
    }
    if (lane == 63) wavesum[wid] = s;
    __syncthreads();

    float offset = 0.0f;
    for (int i = 0; i < wid; ++i) offset += wavesum[i];
    p[t] = s + offset;                     // inclusive prefix over the row

    // exclusive prefix popcount -> valley rank; also total valley count
    int before = __popcll(m & ((1ull << lane) - 1ull));
    int total = 0;
    for (int i = 0; i < 16; ++i) {
        int pc = __popcll(words[i]);
        if (i < wid) before += pc;
        total += pc;
    }
    if (valley) {
        int en = t + 2; if (en > TT) en = TT;
        sst[before + 1] = t;               // start of segment rank+1
        sen[before]     = en;              // end of segment rank
    }
    if (t == 0) {
        sst[0]     = 0;
        sen[total] = TT;
        counts[b]  = total + 1;
    }
    __syncthreads();

    int cnt = total + 1;
    if (t < cnt) {
        int st = sst[t], en = sen[t];
        seg_start[b * TT + t] = st;
        seg_end  [b * TT + t] = en;
        float d = p[en - 1] - (st > 0 ? p[st - 1] : 0.0f);
        den[b * TT + t] = fmaxf(d, 1e-6f);
    }
}

// ---------------- Kernel C: out[b,s,:] = sum_t ws*x / den  (+ mask) ---------
// One wave per output row (4 rows / 256-thread block); lane owns 8 contiguous
// floats. t-loop unrolled x2 with independent accumulators for MLP. Output is
// write-once -> nontemporal stores keep x resident in L2/L3 for the re-read.
// The first block of each batch additionally writes that batch's mask row.
__global__ __launch_bounds__(256) void out_kernel(const float* __restrict__ x,
                                                  const float* __restrict__ ws,
                                                  const int* __restrict__ seg_start,
                                                  const int* __restrict__ seg_end,
                                                  const float* __restrict__ den,
                                                  const int* __restrict__ counts,
                                                  const int* __restrict__ seq,
                                                  float* __restrict__ out) {
    // ---- fused new_mask: 256 blocks per batch; block 0 of each writes mask
    if ((blockIdx.x & 255) == 0) {
        int bb = blockIdx.x >> 8;
        int maxc = 0;
        #pragma unroll
        for (int i = 0; i < BB; ++i) maxc = max(maxc, counts[i]);
        float l0 = (float)seq[0];
        float v  = ((float)seq[bb] / l0) * (float)maxc;   // match jnp f32 order
        int nl = (int)v;                                  // trunc like astype
        float* mrow = out + (size_t)BB * TT * FF + (size_t)bb * TT;
        int s4 = threadIdx.x * 4;
        f32x4 mv;
        mv.x = (s4 + 0 < nl) ? 1.0f : 0.0f;
        mv.y = (s4 + 1 < nl) ? 1.0f : 0.0f;
        mv.z = (s4 + 2 < nl) ? 1.0f : 0.0f;
        mv.w = (s4 + 3 < nl) ? 1.0f : 0.0f;
        nt_store4(mrow + s4, mv);
    }

    int wid  = threadIdx.x >> 6;
    int lane = threadIdx.x & 63;
    int bs = blockIdx.x * 4 + wid;        // b*1024 + s
    int b  = bs >> 10;
    int s  = bs & 1023;
    float* orow = out + (size_t)bs * FF + lane * 8;
    if (s >= counts[b]) {                 // zero-filled unused segment rows
        f32x4 z = 0.0f;
        nt_store4(orow, z);
        nt_store4(orow + 4, z);
        return;
    }
    int st = seg_start[bs], en = seg_end[bs];
    float inv = 1.0f / den[bs];
    const f32x4* xb = (const f32x4*)(x + (size_t)b * TT * FF) + lane * 2;
    const float* wsr = ws + b * TT;
    f32x4 a0 = 0.0f, a1 = 0.0f, c0 = 0.0f, c1 = 0.0f;
    int t = st;
    for (; t + 2 <= en; t += 2) {         // x2 unroll: 4 independent loads in flight
        float w0 = wsr[t], w1 = wsr[t + 1];
        f32x4 p0 = xb[(size_t)t * (FF / 4)];
        f32x4 p1 = xb[(size_t)t * (FF / 4) + 1];
        f32x4 q0 = xb[(size_t)(t + 1) * (FF / 4)];
        f32x4 q1 = xb[(size_t)(t + 1) * (FF / 4) + 1];
        a0 += w0 * p0; a1 += w0 * p1;
        c0 += w1 * q0; c1 += w1 * q1;
    }
    if (t < en) {
        float w0 = wsr[t];
        a0 += w0 * xb[(size_t)t * (FF / 4)];
        a1 += w0 * xb[(size_t)t * (FF / 4) + 1];
    }
    a0 += c0; a1 += c1;
    nt_store4(orow,     a0 * inv);
    nt_store4(orow + 4, a1 * inv);
}

extern "C" void kernel_launch(void* const* d_in, const int* in_sizes, int n_in,
                              void* d_out, int out_size, void* d_ws, size_t ws_size,
                              hipStream_t stream) {
    const float* x    = (const float*)d_in[0];
    const float* aw   = (const float*)d_in[1];
    const float* ab   = (const float*)d_in[2];
    const int*   seq  = (const int*)d_in[3];
    float* out = (float*)d_out;

    // workspace layout (floats): ws[32768] | den[32768] | sstart[32768] |
    //                            send[32768] | counts[32]
    float* ws     = (float*)d_ws;
    float* den    = ws + BB * TT;
    int*   sstart = (int*)(ws + 2 * BB * TT);
    int*   send   = (int*)(ws + 3 * BB * TT);
    int*   counts = (int*)(ws + 4 * BB * TT);

    gate_kernel<<<BB * TT / 4, 256, 0, stream>>>(x, aw, ab, ws);
    seg_kernel<<<BB, 1024, 0, stream>>>(ws, sstart, send, den, counts);
    out_kernel<<<BB * TT / 4, 256, 0, stream>>>(x, ws, sstart, send, den, counts,
                                                seq, out);
}

// Round 4
// 40.343 us; speedup vs baseline: 2.0860x; 1.1016x over previous
//
#include <hip/hip_runtime.h>

#define TT 1024
#define FF 512
#define BB 32
#define MAXSEG 513   // valleys are never adjacent -> cnt <= T/2 + 1

typedef float f32x4 __attribute__((ext_vector_type(4)));

__device__ __forceinline__ void nt_store4(float* p, f32x4 v) {
    __builtin_nontemporal_store(v, (f32x4*)p);
}

// ---------------- Kernel A: ws[b,t] = sigmoid(x[b,t,:] . w + bias) ----------
// One wave (64 lanes) per row; lane i handles 8 contiguous floats (2x float4).
// Double accumulation: closest to exact dot -> minimizes strict-< valley tie
// flips vs the numpy reference. At the 64 MB cold-read HBM floor (~10 us).
__global__ __launch_bounds__(256) void gate_kernel(const float* __restrict__ x,
                                                   const float* __restrict__ w,
                                                   const float* __restrict__ bias,
                                                   float* __restrict__ ws) {
    int wid  = threadIdx.x >> 6;
    int lane = threadIdx.x & 63;
    int row  = blockIdx.x * 4 + wid;              // 0 .. 32767
    const float4* xr = (const float4*)(x + (size_t)row * FF);
    const float4* wr = (const float4*)w;
    float4 x0 = xr[lane * 2],     x1 = xr[lane * 2 + 1];
    float4 w0 = wr[lane * 2],     w1 = wr[lane * 2 + 1];
    double acc = (double)x0.x * w0.x + (double)x0.y * w0.y +
                 (double)x0.z * w0.z + (double)x0.w * w0.w +
                 (double)x1.x * w1.x + (double)x1.y * w1.y +
                 (double)x1.z * w1.z + (double)x1.w * w1.w;
    #pragma unroll
    for (int off = 32; off; off >>= 1) acc += __shfl_down(acc, off);
    if (lane == 0) {
        float z = (float)acc + bias[0];
        ws[row] = 1.0f / (1.0f + expf(-z));
    }
}

// ---------------- Kernel B: per-batch valley detect + segment build ---------
// Fully parallel: valley rank via prefix-popcount of ballot words; valley with
// rank r at position v is the START of segment r+1 and the END of segment r
// (min(v+2,T)). den from an in-LDS inclusive prefix sum of ws.
__global__ __launch_bounds__(1024) void seg_kernel(const float* __restrict__ ws,
                                                   int* __restrict__ seg_start,
                                                   int* __restrict__ seg_end,
                                                   float* __restrict__ den,
                                                   int* __restrict__ counts) {
    int b = blockIdx.x, t = threadIdx.x;
    __shared__ float w[TT];
    __shared__ float p[TT];
    __shared__ unsigned long long words[16];
    __shared__ float wavesum[16];
    __shared__ int sst[MAXSEG];
    __shared__ int sen[MAXSEG];

    w[t] = ws[b * TT + t];
    __syncthreads();

    float wt = w[t];
    bool valley = (t > 0) && (t < TT - 1) && (wt < w[t - 1]) && (wt < w[t + 1]);
    unsigned long long m = __ballot(valley);
    int wid = t >> 6, lane = t & 63;
    if (lane == 0) words[wid] = m;

    // inclusive wave scan of ws (for den)
    float s = wt;
    #pragma unroll
    for (int off = 1; off < 64; off <<= 1) {
        float v = __shfl_up(s, off);
        if (lane >= off) s += v;
    }
    if (lane == 63) wavesum[wid] = s;
    __syncthreads();

    float offset = 0.0f;
    for (int i = 0; i < wid; ++i) offset += wavesum[i];
    p[t] = s + offset;                     // inclusive prefix over the row

    // exclusive prefix popcount -> valley rank; also total valley count
    int before = __popcll(m & ((1ull << lane) - 1ull));
    int total = 0;
    for (int i = 0; i < 16; ++i) {
        int pc = __popcll(words[i]);
        if (i < wid) before += pc;
        total += pc;
    }
    if (valley) {
        int en = t + 2; if (en > TT) en = TT;
        sst[before + 1] = t;               // start of segment rank+1
        sen[before]     = en;              // end of segment rank
    }
    if (t == 0) {
        sst[0]     = 0;
        sen[total] = TT;
        counts[b]  = total + 1;
    }
    __syncthreads();

    int cnt = total + 1;
    if (t < cnt) {
        int st = sst[t], en = sen[t];
        seg_start[b * TT + t] = st;
        seg_end  [b * TT + t] = en;
        float d = p[en - 1] - (st > 0 ? p[st - 1] : 0.0f);
        den[b * TT + t] = fmaxf(d, 1e-6f);
    }
}

// ---------------- Kernel C: out[b,s,:] = sum_t ws*x / den  (+ mask) ---------
// One wave per output row; XCD-swizzled block index so each XCD owns 4
// contiguous batches (overlapping segment reads hit its own L2). Live rows:
// branch-free 8-row predicated unroll -> 16 independent loads in flight
// before any dependent FMA; dynamic tail only for the rare len>8 segment.
__global__ __launch_bounds__(256) void out_kernel(const float* __restrict__ x,
                                                  const float* __restrict__ ws,
                                                  const int* __restrict__ seg_start,
                                                  const int* __restrict__ seg_end,
                                                  const float* __restrict__ den,
                                                  const int* __restrict__ counts,
                                                  const int* __restrict__ seq,
                                                  float* __restrict__ out) {
    int bid = blockIdx.x;

    // ---- fused new_mask: 32 designated blocks write the [B,T] mask
    if ((bid & 255) == 0) {
        int bb = bid >> 8;
        int maxc = 0;
        #pragma unroll
        for (int i = 0; i < BB; ++i) maxc = max(maxc, counts[i]);
        float l0 = (float)seq[0];
        float v  = ((float)seq[bb] / l0) * (float)maxc;   // match jnp f32 order
        int nl = (int)v;                                  // trunc like astype
        float* mrow = out + (size_t)BB * TT * FF + (size_t)bb * TT;
        int s4 = threadIdx.x * 4;
        f32x4 mv;
        mv.x = (s4 + 0 < nl) ? 1.0f : 0.0f;
        mv.y = (s4 + 1 < nl) ? 1.0f : 0.0f;
        mv.z = (s4 + 2 < nl) ? 1.0f : 0.0f;
        mv.w = (s4 + 3 < nl) ? 1.0f : 0.0f;
        nt_store4(mrow + s4, mv);
    }

    // XCD-aware bijective swizzle: 8192 blocks, 8 XCDs -> XCD k gets the
    // contiguous swz range [k*1024, (k+1)*1024) = 4 batches (8 MB window).
    int swz = (bid & 7) * (BB * TT / 4 / 8) + (bid >> 3);

    int wid  = threadIdx.x >> 6;
    int lane = threadIdx.x & 63;
    int bs = swz * 4 + wid;               // b*1024 + s
    int b  = bs >> 10;
    int s  = bs & 1023;
    float* orow = out + (size_t)bs * FF + lane * 8;
    if (s >= counts[b]) {                 // zero-filled unused segment rows
        f32x4 z = 0.0f;
        nt_store4(orow, z);
        nt_store4(orow + 4, z);
        return;
    }
    int st = seg_start[bs], en = seg_end[bs];
    float inv = 1.0f / den[bs];
    const float* xb  = x + (size_t)b * TT * FF + lane * 8;
    const float* wsr = ws + b * TT;
    f32x4 a0 = 0.0f, a1 = 0.0f;
    // 8-row predicated unroll: all 16 loads independent, issued up front.
    #pragma unroll
    for (int k = 0; k < 8; ++k) {
        int t  = st + k;
        int tc = t < en ? t : en - 1;     // clamp: safe re-read, L1-hit
        float wt = t < en ? wsr[tc] : 0.0f;
        const f32x4* xr = (const f32x4*)(xb + (size_t)tc * FF);
        a0 += wt * xr[0];
        a1 += wt * xr[1];
    }
    // rare tail (len > 8, ~10% of live rows)
    for (int t = st + 8; t < en; ++t) {
        float wt = wsr[t];
        const f32x4* xr = (const f32x4*)(xb + (size_t)t * FF);
        a0 += wt * xr[0];
        a1 += wt * xr[1];
    }
    nt_store4(orow,     a0 * inv);
    nt_store4(orow + 4, a1 * inv);
}

extern "C" void kernel_launch(void* const* d_in, const int* in_sizes, int n_in,
                              void* d_out, int out_size, void* d_ws, size_t ws_size,
                              hipStream_t stream) {
    const float* x    = (const float*)d_in[0];
    const float* aw   = (const float*)d_in[1];
    const float* ab   = (const float*)d_in[2];
    const int*   seq  = (const int*)d_in[3];
    float* out = (float*)d_out;

    // workspace layout (floats): ws[32768] | den[32768] | sstart[32768] |
    //                            send[32768] | counts[32]
    float* ws     = (float*)d_ws;
    float* den    = ws + BB * TT;
    int*   sstart = (int*)(ws + 2 * BB * TT);
    int*   send   = (int*)(ws + 3 * BB * TT);
    int*   counts = (int*)(ws + 4 * BB * TT);

    gate_kernel<<<BB * TT / 4, 256, 0, stream>>>(x, aw, ab, ws);
    seg_kernel<<<BB, 1024, 0, stream>>>(ws, sstart, send, den, counts);
    out_kernel<<<BB * TT / 4, 256, 0, stream>>>(x, ws, sstart, send, den, counts,
                                                seq, out);
}